// Round 2
// baseline (6594.614 us; speedup 1.0000x reference)
//
#include <hip/hip_runtime.h>

#define B_   4
#define C_   192
#define E_   768
#define H0   64
#define H_   128
#define HW   (H_*H_)        // 16384
#define PLANE0 (H0*H0)      // 4096
#define NPIX (B_*HW)        // 65536
#define NOUT (B_*C_*HW)     // 12582912

// ws layout (bytes) — small + mask-critical buffers FIRST (total 16.5 MB)
#define OFF_S    0u          // NPIX f32   = 262,144
#define OFF_FAC  262144u     // NPIX f32
#define OFF_MH   524288u     // NPIX f32
#define OFF_MU   786432u     // B*C*PLANE0 u8 = 3,145,728
#define OFF_M1   3932160u    // NOUT u8       = 12,582,912
// end: 16,515,072 B

// d_out (25,165,824 f32) usage timeline:
//   [0:NOUT]      pre (k_idwt..k_cast)  -> y (k_mbconv..k_gdn) -> final out
//   [NOUT:2NOUT]  xm  (k_cast..k_mbconv)                       -> final mask

// ---------------- K1: partial IDWT + mask union ----------------
__global__ __launch_bounds__(256) void k_idwt(
    const float* __restrict__ ll, const float* __restrict__ lh,
    const float* __restrict__ hl, const float* __restrict__ hh,
    const int* __restrict__ llm, const int* __restrict__ m1,
    const int* __restrict__ m2, const int* __restrict__ m3,
    float* __restrict__ pre, unsigned char* __restrict__ mu)
{
    const float G0c[7] = {-0.091271763114f,-0.057543526228f,0.591271763114f,1.115087052457f,
                          0.591271763114f,-0.057543526228f,-0.091271763114f};
    const float G1c[9] = {0.026748757411f,0.016864118443f,-0.078223266529f,-0.266864118443f,
                          0.602949018236f,-0.266864118443f,-0.078223266529f,0.016864118443f,
                          0.026748757411f};
    __shared__ float lo[H_*H0];
    __shared__ float hi[H_*H0];
    const int bc = blockIdx.x;               // b*C + c
    const int base = bc * PLANE0;
    const int t = threadIdx.x;
    // vertical pass: out rows o=0..127 over 64 cols
    for (int idx = t; idx < H_*H0; idx += 256) {
        int o = idx >> 6, j = idx & 63;
        float alo = 0.f, ahi = 0.f;
        #pragma unroll
        for (int k = 0; k < 7; ++k) {
            int d = o + k - 3;
            if (d >= 0 && d <= 2*H0-2 && !(d & 1)) {
                int q = base + (d >> 1)*H0 + j;
                alo += G0c[k] * ll[q] * (float)llm[q];
                ahi += G0c[k] * hl[q] * (float)m2[q];
            }
        }
        #pragma unroll
        for (int k = 0; k < 9; ++k) {
            int d = o + k - 4;
            if (d >= 0 && d <= 2*H0-2 && !(d & 1)) {
                int q = base + (d >> 1)*H0 + j;
                alo += G1c[k] * lh[q] * (float)m1[q];
                ahi += G1c[k] * hh[q] * (float)m3[q];
            }
        }
        lo[idx] = alo; hi[idx] = ahi;
    }
    // mask union (u8)
    for (int idx = t; idx < PLANE0; idx += 256) {
        int q = base + idx;
        mu[q] = (unsigned char)((llm[q] | m1[q] | m2[q] | m3[q]) ? 1 : 0);
    }
    __syncthreads();
    // horizontal pass
    const size_t ob = (size_t)bc * HW;
    for (int idx = t; idx < HW; idx += 256) {
        int o = idx >> 7, q = idx & 127;
        const float* lr = lo + o*H0;
        const float* hr = hi + o*H0;
        float v = 0.f;
        #pragma unroll
        for (int k = 0; k < 7; ++k) {
            int d = q + k - 3;
            if (d >= 0 && d <= 2*H0-2 && !(d & 1)) v += G0c[k] * lr[d >> 1];
        }
        #pragma unroll
        for (int k = 0; k < 9; ++k) {
            int d = q + k - 4;
            if (d >= 0 && d <= 2*H0-2 && !(d & 1)) v += G1c[k] * hr[d >> 1];
        }
        pre[ob + idx] = v;
    }
}

// ---------------- K2: depthwise 3x3 partial conv (cast) ----------------
// xm := x * mask1  (= renormalized conv + b_cast, inside valid; 0 outside)
__global__ __launch_bounds__(256) void k_cast(
    const float* __restrict__ pre, const unsigned char* __restrict__ mu,
    const float* __restrict__ wc, const float* __restrict__ bcast,
    float* __restrict__ xm, unsigned char* __restrict__ m1out)
{
    int idx = blockIdx.x*256 + threadIdx.x;
    if (idx >= NOUT) return;
    int j = idx & 127;
    int i = (idx >> 7) & 127;
    int c = (idx >> 14) % C_;
    int b = idx / (C_*HW);
    const size_t pb = (size_t)(b*C_ + c) * HW;
    const size_t mb = (size_t)(b*C_ + c) * PLANE0;
    float o = 0.f, s = 0.f;
    #pragma unroll
    for (int di = -1; di <= 1; ++di) {
        int gi = i + di; if ((unsigned)gi >= (unsigned)H_) continue;
        #pragma unroll
        for (int dj = -1; dj <= 1; ++dj) {
            int gj = j + dj; if ((unsigned)gj >= (unsigned)H_) continue;
            float m0 = (float)mu[mb + (gi >> 1)*H0 + (gj >> 1)];
            s += m0;
            o += m0 * pre[pb + gi*H_ + gj] * wc[c*9 + (di+1)*3 + (dj+1)];
        }
    }
    bool valid = s > 0.f;
    xm[idx] = valid ? (o * (9.f / s) + bcast[c]) : 0.f;
    m1out[idx] = valid ? 1 : 0;
}

// ---------------- K3: channel-sum of mask1 ----------------
__global__ __launch_bounds__(128) void k_rowsum(const unsigned char* __restrict__ m1,
                                                float* __restrict__ S)
{
    int bi = blockIdx.x;                // b*128 + i
    int b = bi >> 7, i = bi & 127;
    int j = threadIdx.x;
    float s = 0.f;
    size_t base = (size_t)b*C_*HW + (size_t)i*H_ + j;
    for (int c = 0; c < C_; ++c) s += (float)m1[base + (size_t)c*HW];
    S[bi*H_ + j] = s;
}

// ---------------- K4: window-sum -> expand factor & mh ----------------
__global__ __launch_bounds__(256) void k_facm(const float* __restrict__ S,
                                              float* __restrict__ fac, float* __restrict__ mh)
{
    int px = blockIdx.x*256 + threadIdx.x;
    if (px >= NPIX) return;
    int j = px & 127, i = (px >> 7) & 127, b = px >> 14;
    float w3 = 0.f;
    #pragma unroll
    for (int di = -1; di <= 1; ++di) {
        int gi = i + di; if ((unsigned)gi >= (unsigned)H_) continue;
        #pragma unroll
        for (int dj = -1; dj <= 1; ++dj) {
            int gj = j + dj; if ((unsigned)gj >= (unsigned)H_) continue;
            w3 += S[(b*H_ + gi)*H_ + gj];
        }
    }
    bool v = w3 > 0.f;
    fac[px] = v ? 1728.f / w3 : 0.f;
    mh[px]  = v ? 1.f : 0.f;
}

// ---------------- K5: fused MBConv: expand 3x3 -> SiLU -> proj 1x1 (+residual) -> y ----------------
// Per block: 8x8 pixel tile. 6 passes of 128 e; h chunk kept in LDS, proj accumulated on the fly.
__global__ __launch_bounds__(256) void k_mbconv(
    const float* __restrict__ xm, const float* __restrict__ we,
    const float* __restrict__ be, const float* __restrict__ wp,
    const float* __restrict__ bp, const float* __restrict__ bcast,
    const float* __restrict__ fac, const float* __restrict__ mh,
    const unsigned char* __restrict__ m1, float* __restrict__ y)
{
    __shared__ float smem[9216 + 880 + 8448];   // wlds(128e x 72k) | plds(8c x 10 x 11) | hsh(128e x 66)
    float* wlds = smem;                          // reused as wpl[192][32] during proj phase
    float* plds = smem + 9216;
    float* hsh  = smem + 10096;

    const int blk = blockIdx.x;                  // 1024 = 4b * 16 * 16
    const int b  = blk >> 8;
    const int ti = (blk >> 4) & 15, tj = blk & 15;
    const int i0 = ti*8, j0 = tj*8;
    const int t = threadIdx.x;

    // expand-phase mapping: thread = (pixel-quad px4, e-group eg)
    const int px4 = t & 15, eg = t >> 4;
    const int pi  = px4 >> 1, pj0v = (px4 & 1)*4;   // 4 consecutive pixels in row pi
    const int mbase = b*HW + (i0 + pi)*H_ + (j0 + pj0v);
    float facr[4], mhr[4];
    #pragma unroll
    for (int p = 0; p < 4; ++p) { facr[p] = fac[mbase + p]; mhr[p] = mh[mbase + p]; }

    // proj-phase mapping: thread = (pixel pxl, c-group cg)  [cg wave-uniform]
    const int pxl = t & 63, cg = t >> 6;
    float accy[48];
    #pragma unroll
    for (int r = 0; r < 48; ++r) accy[r] = 0.f;

    for (int pass = 0; pass < 6; ++pass) {
        const int e0 = pass*128;
        float acc[4][8];
        #pragma unroll
        for (int p = 0; p < 4; ++p)
            #pragma unroll
            for (int r = 0; r < 8; ++r) acc[p][r] = 0.f;

        for (int ch = 0; ch < 24; ++ch) {          // 8 input channels (72 k) per chunk
            __syncthreads();                       // prev compute / prev proj reads done
            {   // stage weights: 128 e x 72 k (float4 rows of 18)
                const float4* wsrc = (const float4*)we;
                for (int q = t; q < 2304; q += 256) {
                    int el = q / 18, kq = q % 18;
                    ((float4*)wlds)[el*18 + kq] = wsrc[(size_t)(e0 + el)*432 + ch*18 + kq];
                }
            }
            // stage patch: 8 c x 10 x 10 (zero halo)
            for (int q = t; q < 800; q += 256) {
                int cc = q / 100, rem = q % 100;
                int rr = rem / 10, col = rem % 10;
                int gi = i0 - 1 + rr, gj = j0 - 1 + col;
                float v = 0.f;
                if ((unsigned)gi < (unsigned)H_ && (unsigned)gj < (unsigned)H_)
                    v = xm[((size_t)(b*C_ + ch*8 + cc)*H_ + gi)*H_ + gj];
                plds[cc*110 + rr*11 + col] = v;
            }
            __syncthreads();

            #pragma unroll
            for (int kb = 0; kb < 18; ++kb) {      // 4 k per iter
                float W[8][4];
                #pragma unroll
                for (int r = 0; r < 8; ++r) {
                    float4 w4 = *(const float4*)&wlds[(eg*8 + r)*72 + kb*4];
                    W[r][0] = w4.x; W[r][1] = w4.y; W[r][2] = w4.z; W[r][3] = w4.w;
                }
                #pragma unroll
                for (int kk = 0; kk < 4; ++kk) {
                    const int k  = kb*4 + kk;      // compile-time under unroll
                    const int cc = k / 9, di = (k % 9) / 3, dj = k % 3;
                    const int ro = cc*110 + (pi + di)*11 + (pj0v + dj);
                    float p0 = plds[ro + 0], p1 = plds[ro + 1];
                    float p2 = plds[ro + 2], p3 = plds[ro + 3];
                    #pragma unroll
                    for (int r = 0; r < 8; ++r) {
                        float w = W[r][kk];
                        acc[0][r] = fmaf(w, p0, acc[0][r]);
                        acc[1][r] = fmaf(w, p1, acc[1][r]);
                        acc[2][r] = fmaf(w, p2, acc[2][r]);
                        acc[3][r] = fmaf(w, p3, acc[3][r]);
                    }
                }
            }
        }

        // h = silu(acc*fac + b_exp) * mh  -> hsh[el][pxl]
        #pragma unroll
        for (int p = 0; p < 4; ++p) {
            const int pxw = pi*8 + pj0v + p;
            #pragma unroll
            for (int r = 0; r < 8; ++r) {
                float v = acc[p][r]*facr[p] + be[e0 + eg*8 + r];
                float sl = v / (1.f + __expf(-v));
                hsh[(eg*8 + r)*66 + pxw] = sl * mhr[p];
            }
        }
        __syncthreads();   // hsh complete; expand reads of wlds done -> safe to overwrite

        // proj partial over this 128-e chunk, staged 32 e at a time into wlds region
        for (int elc = 0; elc < 4; ++elc) {
            for (int q = t; q < 6144; q += 256) {  // wpl[192][32]
                int cdx = q >> 5, el = q & 31;
                wlds[q] = wp[(size_t)cdx*E_ + e0 + elc*32 + el];
            }
            __syncthreads();
            #pragma unroll
            for (int e4 = 0; e4 < 8; ++e4) {
                const int elb = elc*32 + e4*4;
                float h0 = hsh[(elb + 0)*66 + pxl];
                float h1 = hsh[(elb + 1)*66 + pxl];
                float h2 = hsh[(elb + 2)*66 + pxl];
                float h3 = hsh[(elb + 3)*66 + pxl];
                #pragma unroll
                for (int r = 0; r < 48; ++r) {
                    const float4 w4 = ((const float4*)wlds)[(cg*48 + r)*8 + e4];
                    accy[r] = fmaf(w4.x, h0, fmaf(w4.y, h1, fmaf(w4.z, h2, fmaf(w4.w, h3, accy[r]))));
                }
            }
            __syncthreads();   // wpl reads done before next staging / next pass
        }
    }

    // epilogue: y = proj + b_proj + x*mask_proj
    const int irow = i0 + (pxl >> 3), jcol = j0 + (pxl & 7);
    const int pix = b*HW + irow*H_ + jcol;
    const float mhv = mh[pix];
    #pragma unroll
    for (int r = 0; r < 48; ++r) {
        const int c = cg*48 + r;
        const size_t xi = ((size_t)(b*C_ + c)*H_ + irow)*H_ + jcol;
        y[xi] = accy[r] + bp[c] + xm[xi] + bcast[c]*(mhv - (float)m1[xi]);
    }
}

// ---------------- K6: GDN (gamma @ y^2, rsqrt), in-place; writes out + mask ----------------
__global__ __launch_bounds__(256) void k_gdn(
    const float* __restrict__ y, const float* __restrict__ gamma,
    const float* __restrict__ beta, const float* __restrict__ mh,
    float* __restrict__ dout)
{
    __shared__ float ylds[192*65];
    __shared__ float glds[192*32];
    const int blk = blockIdx.x;               // 1024 = 4b * 128i * 2
    const int b = blk >> 8;
    const int i = (blk >> 1) & 127;
    const int j0 = (blk & 1) * 64;
    const int t = threadIdx.x;
    const int px = t & 63, g = t >> 6;
    const int m0 = b*HW + i*H_ + j0;
    // stage all 192 channels of y for these 64 pixels (then overwrite in place)
    for (int q = t; q < 12288; q += 256) {
        int c = q >> 6, p = q & 63;
        ylds[c*65 + p] = y[((size_t)(b*C_ + c)*H_ + i)*H_ + j0 + p];
    }
    float acc[48];
    #pragma unroll
    for (int r = 0; r < 48; ++r) acc[r] = 0.f;
    for (int cb = 0; cb < 6; ++cb) {
        __syncthreads();   // ylds ready / previous glds reads done
        for (int q = t; q < 6144; q += 256) {
            int cidx = q >> 5, el = q & 31;
            glds[q] = gamma[cidx*C_ + cb*32 + el];
        }
        __syncthreads();
        #pragma unroll
        for (int eb = 0; eb < 8; ++eb) {
            float y0 = ylds[(cb*32 + eb*4+0)*65 + px]; y0 *= y0;
            float y1 = ylds[(cb*32 + eb*4+1)*65 + px]; y1 *= y1;
            float y2 = ylds[(cb*32 + eb*4+2)*65 + px]; y2 *= y2;
            float y3 = ylds[(cb*32 + eb*4+3)*65 + px]; y3 *= y3;
            #pragma unroll
            for (int r = 0; r < 48; ++r) {
                float4 g4 = *(const float4*)&glds[(g*48 + r)*32 + eb*4];
                acc[r] = fmaf(g4.x, y0, fmaf(g4.y, y1, fmaf(g4.z, y2, fmaf(g4.w, y3, acc[r]))));
            }
        }
    }
    float mhv = mh[m0 + px];
    #pragma unroll
    for (int r = 0; r < 48; ++r) {
        int c = g*48 + r;
        size_t oi = ((size_t)(b*C_ + c)*H_ + i)*H_ + j0 + px;
        float yv = ylds[c*65 + px];
        dout[oi] = (mhv > 0.f) ? yv * rsqrtf(beta[c] + acc[r]) : 0.f;
        dout[(size_t)NOUT + oi] = mhv;
    }
}

extern "C" void kernel_launch(void* const* d_in, const int* in_sizes, int n_in,
                              void* d_out, int out_size, void* d_ws, size_t ws_size,
                              hipStream_t stream)
{
    const float* ll = (const float*)d_in[0];
    const float* b1 = (const float*)d_in[1];
    const float* b2 = (const float*)d_in[2];
    const float* b3 = (const float*)d_in[3];
    const int* llm = (const int*)d_in[4];
    const int* m1i = (const int*)d_in[5];
    const int* m2i = (const int*)d_in[6];
    const int* m3i = (const int*)d_in[7];
    const float* wc    = (const float*)d_in[8];
    const float* bcast = (const float*)d_in[9];
    const float* we    = (const float*)d_in[10];
    const float* be    = (const float*)d_in[11];
    const float* wp    = (const float*)d_in[12];
    const float* bp    = (const float*)d_in[13];
    const float* gamma = (const float*)d_in[14];
    const float* beta  = (const float*)d_in[15];

    char* ws = (char*)d_ws;
    float* S   = (float*)(ws + OFF_S);
    float* fac = (float*)(ws + OFF_FAC);
    float* mh  = (float*)(ws + OFF_MH);
    unsigned char* mu  = (unsigned char*)(ws + OFF_MU);
    unsigned char* m1b = (unsigned char*)(ws + OFF_M1);

    float* outF = (float*)d_out;
    float* pre = outF;              // [0:NOUT], later y, later final out
    float* xm  = outF + NOUT;       // [NOUT:2NOUT], later final mask
    float* y   = outF;

    k_idwt<<<dim3(B_*C_), dim3(256), 0, stream>>>(ll, b1, b2, b3, llm, m1i, m2i, m3i, pre, mu);
    k_cast<<<dim3((NOUT + 255)/256), dim3(256), 0, stream>>>(pre, mu, wc, bcast, xm, m1b);
    k_rowsum<<<dim3(B_*H_), dim3(128), 0, stream>>>(m1b, S);
    k_facm<<<dim3(NPIX/256), dim3(256), 0, stream>>>(S, fac, mh);
    k_mbconv<<<dim3(1024), dim3(256), 0, stream>>>(xm, we, be, wp, bp, bcast, fac, mh, m1b, y);
    k_gdn<<<dim3(1024), dim3(256), 0, stream>>>(y, gamma, beta, mh, outF);
}

// Round 3
// 1413.433 us; speedup vs baseline: 4.6657x; 4.6657x over previous
//
#include <hip/hip_runtime.h>

#define B_   4
#define C_   192
#define E_   768
#define H0   64
#define H_   128
#define HW   (H_*H_)        // 16384
#define PLANE0 (H0*H0)      // 4096
#define NPIX (B_*HW)        // 65536
#define NOUT (B_*C_*HW)     // 12582912

// ws layout (bytes)
#define OFF_S    0u          // NPIX f32   = 262,144
#define OFF_FAC  262144u
#define OFF_MH   524288u
#define OFF_MU   786432u     // B*C*PLANE0 u8 = 3,145,728
#define OFF_M1   3932160u    // NOUT u8       = 12,582,912
#define OFF_WEB2 16515072u   // 9*768*192 bf16 = 2,654,208
#define OFF_WPB  19169280u   // 192*768 bf16   = 294,912
// end: 19,464,192 B

// d_out (2*NOUT f32) timeline:
//   [0:NOUT]      pre (idwt..cast) -> y (mbconv..gdn) -> final out
//   [NOUT:2NOUT]  xm f32 (cast..mbconv)               -> final mask

typedef __attribute__((ext_vector_type(8))) short bf16x8;
typedef __attribute__((ext_vector_type(4))) float f32x4;

__device__ __forceinline__ unsigned short f2bf(float f) {
    unsigned u = __float_as_uint(f);
    u += 0x7FFFu + ((u >> 16) & 1u);   // RNE
    return (unsigned short)(u >> 16);
}

// ---------------- K1: partial IDWT + mask union ----------------
__global__ __launch_bounds__(256) void k_idwt(
    const float* __restrict__ ll, const float* __restrict__ lh,
    const float* __restrict__ hl, const float* __restrict__ hh,
    const int* __restrict__ llm, const int* __restrict__ m1,
    const int* __restrict__ m2, const int* __restrict__ m3,
    float* __restrict__ pre, unsigned char* __restrict__ mu)
{
    const float G0c[7] = {-0.091271763114f,-0.057543526228f,0.591271763114f,1.115087052457f,
                          0.591271763114f,-0.057543526228f,-0.091271763114f};
    const float G1c[9] = {0.026748757411f,0.016864118443f,-0.078223266529f,-0.266864118443f,
                          0.602949018236f,-0.266864118443f,-0.078223266529f,0.016864118443f,
                          0.026748757411f};
    __shared__ float lo[H_*H0];
    __shared__ float hi[H_*H0];
    const int bc = blockIdx.x;
    const int base = bc * PLANE0;
    const int t = threadIdx.x;
    for (int idx = t; idx < H_*H0; idx += 256) {
        int o = idx >> 6, j = idx & 63;
        float alo = 0.f, ahi = 0.f;
        #pragma unroll
        for (int k = 0; k < 7; ++k) {
            int d = o + k - 3;
            if (d >= 0 && d <= 2*H0-2 && !(d & 1)) {
                int q = base + (d >> 1)*H0 + j;
                alo += G0c[k] * ll[q] * (float)llm[q];
                ahi += G0c[k] * hl[q] * (float)m2[q];
            }
        }
        #pragma unroll
        for (int k = 0; k < 9; ++k) {
            int d = o + k - 4;
            if (d >= 0 && d <= 2*H0-2 && !(d & 1)) {
                int q = base + (d >> 1)*H0 + j;
                alo += G1c[k] * lh[q] * (float)m1[q];
                ahi += G1c[k] * hh[q] * (float)m3[q];
            }
        }
        lo[idx] = alo; hi[idx] = ahi;
    }
    for (int idx = t; idx < PLANE0; idx += 256) {
        int q = base + idx;
        mu[q] = (unsigned char)((llm[q] | m1[q] | m2[q] | m3[q]) ? 1 : 0);
    }
    __syncthreads();
    const size_t ob = (size_t)bc * HW;
    for (int idx = t; idx < HW; idx += 256) {
        int o = idx >> 7, q = idx & 127;
        const float* lr = lo + o*H0;
        const float* hr = hi + o*H0;
        float v = 0.f;
        #pragma unroll
        for (int k = 0; k < 7; ++k) {
            int d = q + k - 3;
            if (d >= 0 && d <= 2*H0-2 && !(d & 1)) v += G0c[k] * lr[d >> 1];
        }
        #pragma unroll
        for (int k = 0; k < 9; ++k) {
            int d = q + k - 4;
            if (d >= 0 && d <= 2*H0-2 && !(d & 1)) v += G1c[k] * hr[d >> 1];
        }
        pre[ob + idx] = v;
    }
}

// ---------------- K2: depthwise 3x3 partial conv (cast) ----------------
__global__ __launch_bounds__(256) void k_cast(
    const float* __restrict__ pre, const unsigned char* __restrict__ mu,
    const float* __restrict__ wc, const float* __restrict__ bcast,
    float* __restrict__ xm, unsigned char* __restrict__ m1out)
{
    int idx = blockIdx.x*256 + threadIdx.x;
    if (idx >= NOUT) return;
    int j = idx & 127;
    int i = (idx >> 7) & 127;
    int c = (idx >> 14) % C_;
    int b = idx / (C_*HW);
    const size_t pb = (size_t)(b*C_ + c) * HW;
    const size_t mb = (size_t)(b*C_ + c) * PLANE0;
    float o = 0.f, s = 0.f;
    #pragma unroll
    for (int di = -1; di <= 1; ++di) {
        int gi = i + di; if ((unsigned)gi >= (unsigned)H_) continue;
        #pragma unroll
        for (int dj = -1; dj <= 1; ++dj) {
            int gj = j + dj; if ((unsigned)gj >= (unsigned)H_) continue;
            float m0 = (float)mu[mb + (gi >> 1)*H0 + (gj >> 1)];
            s += m0;
            o += m0 * pre[pb + gi*H_ + gj] * wc[c*9 + (di+1)*3 + (dj+1)];
        }
    }
    bool valid = s > 0.f;
    xm[idx] = valid ? (o * (9.f / s) + bcast[c]) : 0.f;
    m1out[idx] = valid ? 1 : 0;
}

// ---------------- K3: channel-sum of mask1 ----------------
__global__ __launch_bounds__(128) void k_rowsum(const unsigned char* __restrict__ m1,
                                                float* __restrict__ S)
{
    int bi = blockIdx.x;
    int b = bi >> 7, i = bi & 127;
    int j = threadIdx.x;
    float s = 0.f;
    size_t base = (size_t)b*C_*HW + (size_t)i*H_ + j;
    for (int c = 0; c < C_; ++c) s += (float)m1[base + (size_t)c*HW];
    S[bi*H_ + j] = s;
}

// ---------------- K4: window-sum -> expand factor & mh ----------------
__global__ __launch_bounds__(256) void k_facm(const float* __restrict__ S,
                                              float* __restrict__ fac, float* __restrict__ mh)
{
    int px = blockIdx.x*256 + threadIdx.x;
    if (px >= NPIX) return;
    int j = px & 127, i = (px >> 7) & 127, b = px >> 14;
    float w3 = 0.f;
    #pragma unroll
    for (int di = -1; di <= 1; ++di) {
        int gi = i + di; if ((unsigned)gi >= (unsigned)H_) continue;
        #pragma unroll
        for (int dj = -1; dj <= 1; ++dj) {
            int gj = j + dj; if ((unsigned)gj >= (unsigned)H_) continue;
            w3 += S[(b*H_ + gi)*H_ + gj];
        }
    }
    bool v = w3 > 0.f;
    fac[px] = v ? 1728.f / w3 : 0.f;
    mh[px]  = v ? 1.f : 0.f;
}

// ---------------- K4b: one-time weight convert/permute to bf16 ----------------
// web2[r][e][c] = bf16(we[e][c*9+r]);  wpb[c][e] = bf16(wp[c][e])
__global__ __launch_bounds__(256) void k_wcvt(const float* __restrict__ we,
                                              const float* __restrict__ wp,
                                              short* __restrict__ web2,
                                              short* __restrict__ wpb)
{
    int idx = blockIdx.x*256 + threadIdx.x;
    const int NW = 9*E_*C_;            // 1,327,104
    if (idx < NW) {
        int r = idx / (E_*C_);
        int rem = idx % (E_*C_);
        int e = rem / C_, c = rem % C_;
        web2[idx] = (short)f2bf(we[(size_t)e*1728 + c*9 + r]);
    } else {
        int j = idx - NW;
        if (j < C_*E_) wpb[j] = (short)f2bf(wp[j]);
    }
}

// ---------------- K5: MFMA fused MBConv ----------------
// 8x8 px tile/block; expand (K=1728) in 4 e-passes of 192; h in LDS; proj fused.
__global__ __launch_bounds__(256, 2) void k_mbconv_mfma(
    const float* __restrict__ xm, const short* __restrict__ web2,
    const float* __restrict__ be, const short* __restrict__ wpb,
    const float* __restrict__ bp, const float* __restrict__ bcast,
    const float* __restrict__ fac, const float* __restrict__ mh,
    const unsigned char* __restrict__ m1, float* __restrict__ y)
{
    __shared__ __align__(16) short plds[100*72];   // patch [pos 10x10][cc 64] (pad->72)
    __shared__ __align__(16) short blds[192*72];   // B [row 192][k 64] (pad->72)
    __shared__ __align__(16) short hsh[64*200];    // h [m 64][e 192]; reused as f32 buf[96][66]

    const int blk = blockIdx.x;                    // 1024 = 4b * 16 * 16
    const int b  = blk >> 8;
    const int ti = (blk >> 4) & 15, tj = blk & 15;
    const int i0 = ti*8, j0 = tj*8;
    const int t = threadIdx.x;
    const int w = t >> 6, l = t & 63;
    const int lid = l & 15, lk8 = (l >> 4)*8, lr4 = (l >> 4)*4;

    // A-frag row pixel (m = w*16 + lid)
    const int am  = w*16 + lid;
    const int api = am >> 3, apj = am & 7;

    f32x4 accy[12];
    #pragma unroll
    for (int i = 0; i < 12; ++i) accy[i] = (f32x4){0.f,0.f,0.f,0.f};

    #pragma unroll 1
    for (int pass = 0; pass < 4; ++pass) {
        const int ep = pass*192;
        f32x4 acc[12];
        #pragma unroll
        for (int i = 0; i < 12; ++i) acc[i] = (f32x4){0.f,0.f,0.f,0.f};

        #pragma unroll 1
        for (int sc = 0; sc < 3; ++sc) {           // 64-channel superchunk
            const int c0 = sc*64;
            #pragma unroll 1
            for (int r = 0; r < 9; ++r) {          // tap
                const int ri = r/3, rj = r%3;
                __syncthreads();                   // protect prev reads of plds/blds
                if (r == 0) {
                    // stage patch [100][64] from xm (f32 -> bf16)
                    for (int q = t; q < 800; q += 256) {
                        int pos = q >> 3, cc8 = (q & 7)*8;
                        int rr = pos/10, col = pos - rr*10;
                        int gi = i0 - 1 + rr, gj = j0 - 1 + col;
                        bool inb = ((unsigned)gi < (unsigned)H_) && ((unsigned)gj < (unsigned)H_);
                        bf16x8 v8;
                        #pragma unroll
                        for (int jj = 0; jj < 8; ++jj) {
                            float v = inb ? xm[((size_t)(b*C_ + c0+cc8+jj)*H_ + gi)*H_ + gj] : 0.f;
                            v8[jj] = (short)f2bf(v);
                        }
                        *(bf16x8*)&plds[pos*72 + cc8] = v8;
                    }
                }
                // stage B [192 e][64 cc] from web2[r][ep+e][c0+cc]
                for (int q = t; q < 1536; q += 256) {
                    int e = q >> 3, cc8 = (q & 7)*8;
                    *(bf16x8*)&blds[e*72 + cc8] =
                        *(const bf16x8*)&web2[((size_t)r*E_ + ep + e)*C_ + c0 + cc8];
                }
                __syncthreads();
                const int pos = (api + ri)*10 + (apj + rj);
                #pragma unroll
                for (int hh = 0; hh < 2; ++hh) {   // 2 K-steps of 32
                    bf16x8 a = *(bf16x8*)&plds[pos*72 + hh*32 + lk8];
                    #pragma unroll
                    for (int nf = 0; nf < 12; ++nf) {
                        bf16x8 bb = *(bf16x8*)&blds[(nf*16+lid)*72 + hh*32 + lk8];
                        acc[nf] = __builtin_amdgcn_mfma_f32_16x16x32_bf16(a, bb, acc[nf], 0, 0, 0);
                    }
                }
            }
        }
        // h = silu(acc*fac + be) * mh -> hsh (wave-private rows; no barrier needed)
        {
            float facr[4], mhr[4];
            #pragma unroll
            for (int reg = 0; reg < 4; ++reg) {
                int m = w*16 + lr4 + reg;
                int pix = b*HW + (i0 + (m>>3))*H_ + j0 + (m&7);
                facr[reg] = fac[pix]; mhr[reg] = mh[pix];
            }
            #pragma unroll
            for (int nf = 0; nf < 12; ++nf) {
                float bev = be[ep + nf*16 + lid];
                #pragma unroll
                for (int reg = 0; reg < 4; ++reg) {
                    int m = w*16 + lr4 + reg;
                    float v = acc[nf][reg]*facr[reg] + bev;
                    float sl = v / (1.f + __expf(-v));
                    hsh[m*200 + nf*16 + lid] = (short)f2bf(sl * mhr[reg]);
                }
            }
        }
        // proj partial over this pass's 192 e (6 K-steps of 32)
        #pragma unroll 1
        for (int ks = 0; ks < 6; ++ks) {
            __syncthreads();                       // protect prev blds reads
            for (int q = t; q < 768; q += 256) {   // stage wp chunk [192 c][32 e]
                int c = q >> 2, ee8 = (q & 3)*8;
                *(bf16x8*)&blds[c*72 + ee8] =
                    *(const bf16x8*)&wpb[(size_t)c*E_ + ep + ks*32 + ee8];
            }
            __syncthreads();
            bf16x8 a = *(bf16x8*)&hsh[(w*16+lid)*200 + ks*32 + lk8];
            #pragma unroll
            for (int nf = 0; nf < 12; ++nf) {
                bf16x8 bb = *(bf16x8*)&blds[(nf*16+lid)*72 + lk8];
                accy[nf] = __builtin_amdgcn_mfma_f32_16x16x32_bf16(a, bb, accy[nf], 0, 0, 0);
            }
        }
    }

    // epilogue: y = proj + bp + xm + bcast*(mh - m1), transposed through LDS
    float* buf = (float*)hsh;
    #pragma unroll
    for (int half = 0; half < 2; ++half) {
        __syncthreads();                           // protect hsh/buf prior reads
        #pragma unroll
        for (int nf6 = 0; nf6 < 6; ++nf6) {
            const int nf = half*6 + nf6;
            #pragma unroll
            for (int reg = 0; reg < 4; ++reg)
                buf[(nf6*16+lid)*66 + (w*16 + lr4 + reg)] = accy[nf][reg];
        }
        __syncthreads();
        for (int q = t; q < 768; q += 256) {       // 96 c x 8 rows
            int cl = q >> 3, pi = q & 7;
            int c = half*96 + cl;
            int gi = i0 + pi;
            size_t gb = ((size_t)(b*C_ + c)*H_ + gi)*H_ + j0;
            int mb2 = b*HW + gi*H_ + j0;
            float bpc = bp[c], bcc = bcast[c];
            #pragma unroll
            for (int jj = 0; jj < 8; ++jj) {
                float pv  = buf[cl*66 + pi*8 + jj];
                float mhv = mh[mb2 + jj];
                float m1v = (float)m1[gb + jj];
                y[gb + jj] = pv + bpc + xm[gb + jj] + bcc*(mhv - m1v);
            }
        }
    }
}

// ---------------- K6: GDN (gamma @ y^2, rsqrt), writes out + mask ----------------
__global__ __launch_bounds__(256) void k_gdn(
    const float* __restrict__ y, const float* __restrict__ gamma,
    const float* __restrict__ beta, const float* __restrict__ mh,
    float* __restrict__ dout)
{
    __shared__ float ylds[192*65];
    __shared__ float glds[192*32];
    const int blk = blockIdx.x;
    const int b = blk >> 8;
    const int i = (blk >> 1) & 127;
    const int j0 = (blk & 1) * 64;
    const int t = threadIdx.x;
    const int px = t & 63, g = t >> 6;
    const int m0 = b*HW + i*H_ + j0;
    for (int q = t; q < 12288; q += 256) {
        int c = q >> 6, p = q & 63;
        ylds[c*65 + p] = y[((size_t)(b*C_ + c)*H_ + i)*H_ + j0 + p];
    }
    float acc[48];
    #pragma unroll
    for (int r = 0; r < 48; ++r) acc[r] = 0.f;
    for (int cb = 0; cb < 6; ++cb) {
        __syncthreads();
        for (int q = t; q < 6144; q += 256) {
            int cidx = q >> 5, el = q & 31;
            glds[q] = gamma[cidx*C_ + cb*32 + el];
        }
        __syncthreads();
        #pragma unroll
        for (int eb = 0; eb < 8; ++eb) {
            float y0 = ylds[(cb*32 + eb*4+0)*65 + px]; y0 *= y0;
            float y1 = ylds[(cb*32 + eb*4+1)*65 + px]; y1 *= y1;
            float y2 = ylds[(cb*32 + eb*4+2)*65 + px]; y2 *= y2;
            float y3 = ylds[(cb*32 + eb*4+3)*65 + px]; y3 *= y3;
            #pragma unroll
            for (int r = 0; r < 48; ++r) {
                float4 g4 = *(const float4*)&glds[(g*48 + r)*32 + eb*4];
                acc[r] = fmaf(g4.x, y0, fmaf(g4.y, y1, fmaf(g4.z, y2, fmaf(g4.w, y3, acc[r]))));
            }
        }
    }
    float mhv = mh[m0 + px];
    #pragma unroll
    for (int r = 0; r < 48; ++r) {
        int c = g*48 + r;
        size_t oi = ((size_t)(b*C_ + c)*H_ + i)*H_ + j0 + px;
        float yv = ylds[c*65 + px];
        dout[oi] = (mhv > 0.f) ? yv * rsqrtf(beta[c] + acc[r]) : 0.f;
        dout[(size_t)NOUT + oi] = mhv;
    }
}

extern "C" void kernel_launch(void* const* d_in, const int* in_sizes, int n_in,
                              void* d_out, int out_size, void* d_ws, size_t ws_size,
                              hipStream_t stream)
{
    const float* ll = (const float*)d_in[0];
    const float* b1 = (const float*)d_in[1];
    const float* b2 = (const float*)d_in[2];
    const float* b3 = (const float*)d_in[3];
    const int* llm = (const int*)d_in[4];
    const int* m1i = (const int*)d_in[5];
    const int* m2i = (const int*)d_in[6];
    const int* m3i = (const int*)d_in[7];
    const float* wc    = (const float*)d_in[8];
    const float* bcast = (const float*)d_in[9];
    const float* we    = (const float*)d_in[10];
    const float* be    = (const float*)d_in[11];
    const float* wp    = (const float*)d_in[12];
    const float* bp    = (const float*)d_in[13];
    const float* gamma = (const float*)d_in[14];
    const float* beta  = (const float*)d_in[15];

    char* ws = (char*)d_ws;
    float* S   = (float*)(ws + OFF_S);
    float* fac = (float*)(ws + OFF_FAC);
    float* mh  = (float*)(ws + OFF_MH);
    unsigned char* mu  = (unsigned char*)(ws + OFF_MU);
    unsigned char* m1b = (unsigned char*)(ws + OFF_M1);
    short* web2 = (short*)(ws + OFF_WEB2);
    short* wpb  = (short*)(ws + OFF_WPB);

    float* outF = (float*)d_out;
    float* pre = outF;              // [0:NOUT] -> y -> final out
    float* xm  = outF + NOUT;       // [NOUT:2NOUT] f32 -> final mask
    float* y   = outF;

    k_wcvt<<<dim3(5760), dim3(256), 0, stream>>>(we, wp, web2, wpb);
    k_idwt<<<dim3(B_*C_), dim3(256), 0, stream>>>(ll, b1, b2, b3, llm, m1i, m2i, m3i, pre, mu);
    k_cast<<<dim3((NOUT + 255)/256), dim3(256), 0, stream>>>(pre, mu, wc, bcast, xm, m1b);
    k_rowsum<<<dim3(B_*H_), dim3(128), 0, stream>>>(m1b, S);
    k_facm<<<dim3(NPIX/256), dim3(256), 0, stream>>>(S, fac, mh);
    k_mbconv_mfma<<<dim3(1024), dim3(256), 0, stream>>>(xm, web2, be, wpb, bp, bcast, fac, mh, m1b, y);
    k_gdn<<<dim3(1024), dim3(256), 0, stream>>>(y, gamma, beta, mh, outF);
}

// Round 6
// 881.663 us; speedup vs baseline: 7.4797x; 1.6031x over previous
//
#include <hip/hip_runtime.h>

#define B_   4
#define C_   192
#define E_   768
#define H0   64
#define H_   128
#define HW   (H_*H_)        // 16384
#define PLANE0 (H0*H0)      // 4096
#define NPIX (B_*HW)        // 65536
#define NOUT (B_*C_*HW)     // 12582912

// halo-padded pixel-major xm: [b][130][130][192] bf16, lives in d_out[0:NOUT]
#define XTW  130
#define XTPL (XTW*XTW)       // 16,900
#define XT_SHORTS (B_*XTPL*192)   // 12,979,200 shorts = 25,958,400 B  (< NOUT*4)

// ws layout (bytes)
#define OFF_S    0u
#define OFF_FAC  262144u
#define OFF_MH   524288u
#define OFF_MU   786432u     // u8 3,145,728
#define OFF_M1   3932160u    // u8 12,582,912
#define OFF_WEB3 16515072u   // 9*768*192 bf16 = 2,654,208 (pre-permuted+swizzled)
#define OFF_WPB3 19169280u   // 8*192*128 bf16 = 393,216 (16-group padded rows)
#define OFF_GB   19562496u   // 192*192 bf16 = 73,728
// end 19,636,224

// d_out (2*NOUT f32) timeline:
//   [0:NOUT]      pre (idwt..cast) -> xmT bf16 halo (zero16..mbconv) -> final out (gdn)
//   [NOUT:2NOUT]  xm f32 (cast..mbconv epilogue) -> y (mbconv..gdn) -> final mask

typedef __attribute__((ext_vector_type(8))) short bf16x8;
typedef __attribute__((ext_vector_type(4))) float f32x4;

__device__ __forceinline__ unsigned short f2bf(float f) {
    unsigned u = __float_as_uint(f);
    u += 0x7FFFu + ((u >> 16) & 1u);   // RNE
    return (unsigned short)(u >> 16);
}

__device__ __forceinline__ void gll16(const void* g, void* l) {
    __builtin_amdgcn_global_load_lds(
        (const __attribute__((address_space(1))) unsigned int*)g,
        (__attribute__((address_space(3))) unsigned int*)l, 16, 0, 0);
}

// ---------------- K0: zero a 16B-granular region ----------------
__global__ __launch_bounds__(256) void k_zero16(f32x4* __restrict__ p, int n16)
{
    int idx = blockIdx.x*256 + threadIdx.x;
    if (idx < n16) p[idx] = (f32x4){0.f,0.f,0.f,0.f};
}

// ---------------- K1: partial IDWT + mask union ----------------
__global__ __launch_bounds__(256) void k_idwt(
    const float* __restrict__ ll, const float* __restrict__ lh,
    const float* __restrict__ hl, const float* __restrict__ hh,
    const int* __restrict__ llm, const int* __restrict__ m1,
    const int* __restrict__ m2, const int* __restrict__ m3,
    float* __restrict__ pre, unsigned char* __restrict__ mu)
{
    const float G0c[7] = {-0.091271763114f,-0.057543526228f,0.591271763114f,1.115087052457f,
                          0.591271763114f,-0.057543526228f,-0.091271763114f};
    const float G1c[9] = {0.026748757411f,0.016864118443f,-0.078223266529f,-0.266864118443f,
                          0.602949018236f,-0.266864118443f,-0.078223266529f,0.016864118443f,
                          0.026748757411f};
    __shared__ float lo[H_*H0];
    __shared__ float hi[H_*H0];
    const int bc = blockIdx.x;
    const int base = bc * PLANE0;
    const int t = threadIdx.x;
    for (int idx = t; idx < H_*H0; idx += 256) {
        int o = idx >> 6, j = idx & 63;
        float alo = 0.f, ahi = 0.f;
        #pragma unroll
        for (int k = 0; k < 7; ++k) {
            int d = o + k - 3;
            if (d >= 0 && d <= 2*H0-2 && !(d & 1)) {
                int q = base + (d >> 1)*H0 + j;
                alo += G0c[k] * ll[q] * (float)llm[q];
                ahi += G0c[k] * hl[q] * (float)m2[q];
            }
        }
        #pragma unroll
        for (int k = 0; k < 9; ++k) {
            int d = o + k - 4;
            if (d >= 0 && d <= 2*H0-2 && !(d & 1)) {
                int q = base + (d >> 1)*H0 + j;
                alo += G1c[k] * lh[q] * (float)m1[q];
                ahi += G1c[k] * hh[q] * (float)m3[q];
            }
        }
        lo[idx] = alo; hi[idx] = ahi;
    }
    for (int idx = t; idx < PLANE0; idx += 256) {
        int q = base + idx;
        mu[q] = (unsigned char)((llm[q] | m1[q] | m2[q] | m3[q]) ? 1 : 0);
    }
    __syncthreads();
    const size_t ob = (size_t)bc * HW;
    for (int idx = t; idx < HW; idx += 256) {
        int o = idx >> 7, q = idx & 127;
        const float* lr = lo + o*H0;
        const float* hr = hi + o*H0;
        float v = 0.f;
        #pragma unroll
        for (int k = 0; k < 7; ++k) {
            int d = q + k - 3;
            if (d >= 0 && d <= 2*H0-2 && !(d & 1)) v += G0c[k] * lr[d >> 1];
        }
        #pragma unroll
        for (int k = 0; k < 9; ++k) {
            int d = q + k - 4;
            if (d >= 0 && d <= 2*H0-2 && !(d & 1)) v += G1c[k] * hr[d >> 1];
        }
        pre[ob + idx] = v;
    }
}

// ---------------- K2: depthwise 3x3 partial conv (cast) ----------------
__global__ __launch_bounds__(256) void k_cast(
    const float* __restrict__ pre, const unsigned char* __restrict__ mu,
    const float* __restrict__ wc, const float* __restrict__ bcast,
    float* __restrict__ xm, unsigned char* __restrict__ m1out)
{
    int idx = blockIdx.x*256 + threadIdx.x;
    if (idx >= NOUT) return;
    int j = idx & 127;
    int i = (idx >> 7) & 127;
    int c = (idx >> 14) % C_;
    int b = idx / (C_*HW);
    const size_t pb = (size_t)(b*C_ + c) * HW;
    const size_t mb = (size_t)(b*C_ + c) * PLANE0;
    float o = 0.f, s = 0.f;
    #pragma unroll
    for (int di = -1; di <= 1; ++di) {
        int gi = i + di; if ((unsigned)gi >= (unsigned)H_) continue;
        #pragma unroll
        for (int dj = -1; dj <= 1; ++dj) {
            int gj = j + dj; if ((unsigned)gj >= (unsigned)H_) continue;
            float m0 = (float)mu[mb + (gi >> 1)*H0 + (gj >> 1)];
            s += m0;
            o += m0 * pre[pb + gi*H_ + gj] * wc[c*9 + (di+1)*3 + (dj+1)];
        }
    }
    bool valid = s > 0.f;
    xm[idx] = valid ? (o * (9.f / s) + bcast[c]) : 0.f;
    m1out[idx] = valid ? 1 : 0;
}

// ---------------- K3: channel-sum of mask1 ----------------
__global__ __launch_bounds__(128) void k_rowsum(const unsigned char* __restrict__ m1,
                                                float* __restrict__ S)
{
    int bi = blockIdx.x;
    int b = bi >> 7, i = bi & 127;
    int j = threadIdx.x;
    float s = 0.f;
    size_t base = (size_t)b*C_*HW + (size_t)i*H_ + j;
    for (int c = 0; c < C_; ++c) s += (float)m1[base + (size_t)c*HW];
    S[bi*H_ + j] = s;
}

// ---------------- K4: window-sum -> expand factor & mh ----------------
__global__ __launch_bounds__(256) void k_facm(const float* __restrict__ S,
                                              float* __restrict__ fac, float* __restrict__ mh)
{
    int px = blockIdx.x*256 + threadIdx.x;
    if (px >= NPIX) return;
    int j = px & 127, i = (px >> 7) & 127, b = px >> 14;
    float w3 = 0.f;
    #pragma unroll
    for (int di = -1; di <= 1; ++di) {
        int gi = i + di; if ((unsigned)gi >= (unsigned)H_) continue;
        #pragma unroll
        for (int dj = -1; dj <= 1; ++dj) {
            int gj = j + dj; if ((unsigned)gj >= (unsigned)H_) continue;
            w3 += S[(b*H_ + gi)*H_ + gj];
        }
    }
    bool v = w3 > 0.f;
    fac[px] = v ? 1728.f / w3 : 0.f;
    mh[px]  = v ? 1.f : 0.f;
}

// ---------------- K4b: weight convert + permute + XOR-preswizzle ----------------
// web3: [tile=(p*3+sc)*9+r][e 192][c8p 8][8], content c-group = c8p ^ (e&7)   (3-bit, closed)
// wpb3: [ph=p*2+hf][co 192][s 16][8], slot s holds e-group g = s^(co&7) if g<12 else 0
//       (16-slot rows => XOR closed; pad slots never read)
// gb  : gamma bf16 [co][c]
__global__ __launch_bounds__(256) void k_wcvt(const float* __restrict__ we,
                                              const float* __restrict__ wp,
                                              const float* __restrict__ gamma,
                                              short* __restrict__ web3,
                                              short* __restrict__ wpb3,
                                              short* __restrict__ gb)
{
    int idx = blockIdx.x*256 + threadIdx.x;
    const int N1 = 9*E_*C_;          // 1,327,104
    const int N2 = 8*C_*128;         // 196,608
    if (idx < N1) {
        int tile = idx / 12288, rem = idx % 12288;
        int e = rem >> 6, r2 = rem & 63;
        int c8p = r2 >> 3, j = r2 & 7;
        int p = tile / 27, sc = (tile % 27) / 9, r = tile % 9;
        int c = sc*64 + ((c8p ^ (e & 7)) << 3) + j;
        int eg = p*192 + e;
        web3[idx] = (short)f2bf(we[(size_t)eg*1728 + c*9 + r]);
    } else if (idx < N1 + N2) {
        int i2 = idx - N1;
        int ph = i2 / 24576;
        int rem = i2 % 24576;
        int co = rem >> 7;
        int r3v = rem & 127;
        int s = r3v >> 3, j = r3v & 7;
        int g = s ^ (co & 7);
        float v = (g < 12) ? wp[(size_t)co*E_ + ph*96 + (g << 3) + j] : 0.f;
        wpb3[i2] = (short)f2bf(v);
    } else {
        int i3 = idx - N1 - N2;
        if (i3 < C_*C_) gb[i3] = (short)f2bf(gamma[i3]);
    }
}

// ---------------- K4c: xm f32 [c][pix] -> xmT bf16 [b][130][130][192] (interior) ----------------
__global__ __launch_bounds__(256) void k_xmt(const float* __restrict__ xm,
                                             short* __restrict__ xmT)
{
    __shared__ float sm[64*65];
    const int gx = blockIdx.x;           // 3072 = 3 cb * 1024 pb
    const int cb = gx >> 10, pb = gx & 1023;
    const int c0 = cb*64, pix0 = pb*64;
    const int b = pix0 >> 14, pixb = pix0 & 16383;
    const int t = threadIdx.x;
    const int lane6 = t & 63, hi4 = t >> 6;
    #pragma unroll
    for (int it = 0; it < 16; ++it) {
        int r4 = it*4 + hi4;
        sm[r4*65 + lane6] = xm[((size_t)(b*C_ + c0 + r4))*HW + pixb + lane6];
    }
    __syncthreads();
    #pragma unroll
    for (int it = 0; it < 2; ++it) {
        int q = it*256 + t;
        int pp = q >> 3, c8 = q & 7;
        int p = pixb + pp;
        int i = p >> 7, j = p & 127;
        bf16x8 v;
        #pragma unroll
        for (int jj = 0; jj < 8; ++jj) v[jj] = (short)f2bf(sm[(c8*8+jj)*65 + pp]);
        *(bf16x8*)&xmT[((size_t)(b*XTPL + (i+1)*XTW + (j+1)))*192 + c0 + c8*8] = v;
    }
}

// ---------------- K5: MFMA fused MBConv (expand + SiLU + proj + residual) ----------------
// 256 blocks x 512 thr (8 waves). M=256 px (16x16 tile), 4 passes of 192 e.
__global__ __launch_bounds__(512, 2) void k_mbconv(
    const short* __restrict__ xmT, const short* __restrict__ web3,
    const short* __restrict__ wpb3, const float* __restrict__ be,
    const float* __restrict__ bp, const float* __restrict__ bcast,
    const float* __restrict__ fac, const float* __restrict__ mh,
    const unsigned char* __restrict__ m1, float* __restrict__ xmy)
{
    __shared__ __align__(16) char smem[156160];
    short* apat = (short*)smem;                 // [324][64]      41,472 B
    short* bB   = (short*)(smem + 41472);       // [2][192][64]   49,152 B (proj: [192][128])
    short* hB   = (short*)(smem + 90624);       // [256][128]     65,536 B
    float* fbuf = (float*)smem;                 // epi [192][132] 101,376 B

    const int blk = blockIdx.x;          // 256 = 4b * 8 * 8
    const int b = blk >> 6;
    const int ti = (blk >> 3) & 7, tj = blk & 7;
    const int i0 = ti*16, j0 = tj*16;
    const int t = threadIdx.x;
    const int w = t >> 6, l = t & 63;
    const int wm = w >> 1, we_ = w & 1;
    const int m0 = wm * 64;
    const int lo = l & 15, hi = l >> 4;

    f32x4 accy[4][6];
    #pragma unroll
    for (int a = 0; a < 4; ++a)
        #pragma unroll
        for (int n = 0; n < 6; ++n) accy[a][n] = (f32x4){0.f,0.f,0.f,0.f};

    #pragma unroll 1
    for (int p = 0; p < 4; ++p) {
        f32x4 acc[4][6];
        #pragma unroll
        for (int a = 0; a < 4; ++a)
            #pragma unroll
            for (int n = 0; n < 6; ++n) acc[a][n] = (f32x4){0.f,0.f,0.f,0.f};

        #pragma unroll 1
        for (int sc = 0; sc < 3; ++sc) {
            const int c0 = sc*64;
            // issue A-patch gll: 5 full-exec waves of 512, tail 32 via reg+ds_write
            #pragma unroll 1
            for (int it = 0; it < 5; ++it) {
                int q = it*512 + t;
                int pos = q >> 3, c8p = q & 7;
                int rr = pos / 18, cc = pos - rr*18;
                gll16(&xmT[((size_t)(b*XTPL + (i0+rr)*XTW + (j0+cc)))*192 + c0 + ((c8p ^ (pos&7))<<3)],
                      &apat[q*8]);
            }
            if (t < 32) {
                int q = 2560 + t;
                int pos = q >> 3, c8p = q & 7;
                int rr = pos / 18, cc = pos - rr*18;
                bf16x8 v = *(const bf16x8*)&xmT[((size_t)(b*XTPL + (i0+rr)*XTW + (j0+cc)))*192
                                                + c0 + ((c8p ^ (pos&7))<<3)];
                *(bf16x8*)&apat[q*8] = v;
            }
            // issue B tap0
            {
                const size_t tile0 = (size_t)((p*3+sc)*9) * 12288;
                #pragma unroll
                for (int it = 0; it < 3; ++it) {
                    int q = it*512 + t;
                    gll16(&web3[tile0 + q*8], &bB[q*8]);
                }
            }
            #pragma unroll 1
            for (int r = 0; r < 9; ++r) {
                __syncthreads();   // drains vmcnt/lgkmcnt before barrier
                if (r < 8) {
                    const size_t tileN = (size_t)((p*3+sc)*9 + r + 1) * 12288;
                    short* dstb = &bB[((r+1)&1) * 12288];
                    #pragma unroll
                    for (int it = 0; it < 3; ++it) {
                        int q = it*512 + t;
                        gll16(&web3[tileN + q*8], &dstb[q*8]);
                    }
                }
                const int ri = r/3, rj = r - ri*3;
                int posA[4];
                #pragma unroll
                for (int af = 0; af < 4; ++af) {
                    int px = m0 + af*16 + lo;
                    posA[af] = ((px >> 4) + ri)*18 + (px & 15) + rj;
                }
                const short* bcur = &bB[(r&1) * 12288];
                #pragma unroll
                for (int s = 0; s < 2; ++s) {
                    const int c8l = s*4 + hi;
                    bf16x8 a[4], bb[6];
                    #pragma unroll
                    for (int af = 0; af < 4; ++af)
                        a[af] = *(const bf16x8*)&apat[posA[af]*64 + ((c8l ^ (posA[af]&7))<<3)];
                    #pragma unroll
                    for (int nf = 0; nf < 6; ++nf) {
                        int e = we_*96 + nf*16 + lo;
                        bb[nf] = *(const bf16x8*)&bcur[e*64 + ((c8l ^ (e&7))<<3)];
                    }
                    #pragma unroll
                    for (int af = 0; af < 4; ++af)
                        #pragma unroll
                        for (int nf = 0; nf < 6; ++nf)
                            acc[af][nf] = __builtin_amdgcn_mfma_f32_16x16x32_bf16(
                                a[af], bb[nf], acc[af][nf], 0, 0, 0);
                }
            }
            __syncthreads();   // all A/B reads done before next-sc issue
        }

        // ---- silu -> h (halves), fused proj ----
        #pragma unroll 1
        for (int hf = 0; hf < 2; ++hf) {
            if (we_ == hf) {
                #pragma unroll
                for (int af = 0; af < 4; ++af) {
                    #pragma unroll
                    for (int nf = 0; nf < 6; ++nf) {
                        int eh = nf*16 + lo;                 // e within half
                        float bev = be[p*192 + hf*96 + eh];
                        #pragma unroll
                        for (int reg = 0; reg < 4; ++reg) {
                            int mg = m0 + af*16 + hi*4 + reg;
                            int pix = b*HW + (i0 + (mg >> 4))*128 + j0 + (mg & 15);
                            float fr = fac[pix];
                            float v = acc[af][nf][reg]*fr + bev;
                            float hv = (fr > 0.f) ? v / (1.f + __expf(-v)) : 0.f;
                            hB[mg*128 + (((eh>>3) ^ (mg&7))<<3) + (eh&7)] = (short)f2bf(hv);
                        }
                    }
                }
            }
            {   // issue wpb chunk: 3072 granules = 6 x 512, full exec
                const size_t wb0 = (size_t)(p*2 + hf) * 24576;
                #pragma unroll
                for (int it = 0; it < 6; ++it) {
                    int q = it*512 + t;
                    gll16(&wpb3[wb0 + q*8], &bB[q*8]);
                }
            }
            __syncthreads();   // wpb staged + h visible
            #pragma unroll
            for (int ks = 0; ks < 3; ++ks) {
                const int e8l = ks*4 + hi;
                bf16x8 a[4], bb[6];
                #pragma unroll
                for (int af = 0; af < 4; ++af) {
                    int mg = m0 + af*16 + lo;
                    a[af] = *(const bf16x8*)&hB[mg*128 + ((e8l ^ (mg&7))<<3)];
                }
                #pragma unroll
                for (int nf = 0; nf < 6; ++nf) {
                    int co = we_*96 + nf*16 + lo;
                    bb[nf] = *(const bf16x8*)&bB[co*128 + ((e8l ^ (co&7))<<3)];
                }
                #pragma unroll
                for (int af = 0; af < 4; ++af)
                    #pragma unroll
                    for (int nf = 0; nf < 6; ++nf)
                        accy[af][nf] = __builtin_amdgcn_mfma_f32_16x16x32_bf16(
                            a[af], bb[nf], accy[af][nf], 0, 0, 0);
            }
            __syncthreads();   // bB reads done
        }
    }

    // ---- epilogue: y = proj + bp + xm + bcast*(mh - m1), transposed via LDS ----
    #pragma unroll 1
    for (int ph = 0; ph < 2; ++ph) {
        if ((wm >> 1) == ph) {
            #pragma unroll
            for (int af = 0; af < 4; ++af)
                #pragma unroll
                for (int nf = 0; nf < 6; ++nf) {
                    int co = we_*96 + nf*16 + lo;
                    int pxl = (wm&1)*64 + af*16 + hi*4;
                    *(f32x4*)&fbuf[co*132 + pxl] = accy[af][nf];
                }
        }
        __syncthreads();
        #pragma unroll 1
        for (int it = 0; it < 12; ++it) {
            int q = it*512 + t;                  // 6144 = 192co x 32 chunks
            int co = q >> 5, px4 = (q & 31) << 2;
            int px = ph*128 + px4;
            int pi = px >> 4, pj = px & 15;
            size_t gidx = ((size_t)(b*C_ + co))*HW + (size_t)(i0+pi)*128 + j0 + pj;
            int pixg = b*HW + (i0+pi)*128 + j0 + pj;
            f32x4 pv = *(f32x4*)&fbuf[co*132 + px4];
            f32x4 xm4 = *(const f32x4*)&xmy[gidx];
            f32x4 mh4 = *(const f32x4*)&mh[pixg];
            unsigned mu4 = *(const unsigned*)&m1[gidx];
            float bpc = bp[co], bcc = bcast[co];
            f32x4 o;
            #pragma unroll
            for (int k = 0; k < 4; ++k)
                o[k] = pv[k] + bpc + xm4[k] + bcc*(mh4[k] - (float)((mu4 >> (8*k)) & 255u));
            *(f32x4*)&xmy[gidx] = o;
        }
        __syncthreads();
    }
}

// ---------------- K6: MFMA GDN: norm = gamma @ (y^2), out = y*rsqrt(beta+norm), + mask ----------------
__global__ __launch_bounds__(512, 2) void k_gdn(
    const short* __restrict__ gb, const float* __restrict__ beta,
    const float* __restrict__ mh, float* __restrict__ dout)
{
    __shared__ __align__(16) char smem[101376];
    short* aB = (short*)smem;               // [256][104] 53,248
    short* bG = (short*)(smem + 53248);     // [192][104] 39,936
    float* fbuf = (float*)smem;             // [192][132]
    const float* y = dout + NOUT;

    const int blk = blockIdx.x;
    const int b = blk >> 6;
    const int ti = (blk >> 3) & 7, tj = blk & 7;
    const int i0 = ti*16, j0 = tj*16;
    const int t = threadIdx.x;
    const int w = t >> 6, l = t & 63;
    const int wm = w >> 1, we_ = w & 1;
    const int m0 = wm * 64;
    const int lo = l & 15, hi = l >> 4;

    f32x4 acc[4][6];
    #pragma unroll
    for (int a = 0; a < 4; ++a)
        #pragma unroll
        for (int n = 0; n < 6; ++n) acc[a][n] = (f32x4){0.f,0.f,0.f,0.f};

    #pragma unroll 1
    for (int ch = 0; ch < 2; ++ch) {
        __syncthreads();
        // stage A = bf16(y^2) [256 px][96 c]
        #pragma unroll 1
        for (int it = 0; it < 12; ++it) {
            int q = it*512 + t;                 // 6144 = 96c x 64 px-chunks
            int cL = q >> 6, px4 = (q & 63) << 2;
            int c = ch*96 + cL;
            int pi = px4 >> 4, pj = px4 & 15;
            f32x4 yv = *(const f32x4*)&y[((size_t)(b*C_ + c))*HW + (size_t)(i0+pi)*128 + j0 + pj];
            #pragma unroll
            for (int k = 0; k < 4; ++k)
                aB[(px4+k)*104 + cL] = (short)f2bf(yv[k]*yv[k]);
        }
        // stage B = gamma chunk [192 co][96 c]
        #pragma unroll 1
        for (int it = 0; it < 5; ++it) {
            int q = it*512 + t;
            if (q < 2304) {
                int co = q / 12, e8 = q - co*12;
                *(bf16x8*)&bG[co*104 + e8*8] = *(const bf16x8*)&gb[co*192 + ch*96 + e8*8];
            }
        }
        __syncthreads();
        #pragma unroll
        for (int ks = 0; ks < 3; ++ks) {
            const int koff = ks*32 + hi*8;
            bf16x8 a[4], bb[6];
            #pragma unroll
            for (int af = 0; af < 4; ++af)
                a[af] = *(const bf16x8*)&aB[(m0 + af*16 + lo)*104 + koff];
            #pragma unroll
            for (int nf = 0; nf < 6; ++nf)
                bb[nf] = *(const bf16x8*)&bG[(we_*96 + nf*16 + lo)*104 + koff];
            #pragma unroll
            for (int af = 0; af < 4; ++af)
                #pragma unroll
                for (int nf = 0; nf < 6; ++nf)
                    acc[af][nf] = __builtin_amdgcn_mfma_f32_16x16x32_bf16(
                        a[af], bb[nf], acc[af][nf], 0, 0, 0);
        }
    }

    // epilogue
    #pragma unroll 1
    for (int ph = 0; ph < 2; ++ph) {
        __syncthreads();
        if ((wm >> 1) == ph) {
            #pragma unroll
            for (int af = 0; af < 4; ++af)
                #pragma unroll
                for (int nf = 0; nf < 6; ++nf) {
                    int co = we_*96 + nf*16 + lo;
                    int pxl = (wm&1)*64 + af*16 + hi*4;
                    *(f32x4*)&fbuf[co*132 + pxl] = acc[af][nf];
                }
        }
        __syncthreads();
        #pragma unroll 1
        for (int it = 0; it < 12; ++it) {
            int q = it*512 + t;
            int co = q >> 5, px4 = (q & 31) << 2;
            int px = ph*128 + px4;
            int pi = px >> 4, pj = px & 15;
            size_t gidx = ((size_t)(b*C_ + co))*HW + (size_t)(i0+pi)*128 + j0 + pj;
            int pixg = b*HW + (i0+pi)*128 + j0 + pj;
            f32x4 nv = *(f32x4*)&fbuf[co*132 + px4];
            f32x4 yv = *(const f32x4*)&y[gidx];
            f32x4 mh4 = *(const f32x4*)&mh[pixg];
            float bt = beta[co];
            f32x4 o;
            #pragma unroll
            for (int k = 0; k < 4; ++k)
                o[k] = (mh4[k] > 0.f) ? yv[k]*rsqrtf(bt + nv[k]) : 0.f;
            *(f32x4*)&dout[gidx] = o;
            *(f32x4*)&dout[(size_t)NOUT + gidx] = mh4;   // final mask (read y first above)
        }
    }
}

extern "C" void kernel_launch(void* const* d_in, const int* in_sizes, int n_in,
                              void* d_out, int out_size, void* d_ws, size_t ws_size,
                              hipStream_t stream)
{
    const float* ll = (const float*)d_in[0];
    const float* b1 = (const float*)d_in[1];
    const float* b2 = (const float*)d_in[2];
    const float* b3 = (const float*)d_in[3];
    const int* llm = (const int*)d_in[4];
    const int* m1i = (const int*)d_in[5];
    const int* m2i = (const int*)d_in[6];
    const int* m3i = (const int*)d_in[7];
    const float* wc    = (const float*)d_in[8];
    const float* bcast = (const float*)d_in[9];
    const float* we    = (const float*)d_in[10];
    const float* be    = (const float*)d_in[11];
    const float* wp    = (const float*)d_in[12];
    const float* bp    = (const float*)d_in[13];
    const float* gamma = (const float*)d_in[14];
    const float* beta  = (const float*)d_in[15];

    char* ws = (char*)d_ws;
    float* S   = (float*)(ws + OFF_S);
    float* fac = (float*)(ws + OFF_FAC);
    float* mh  = (float*)(ws + OFF_MH);
    unsigned char* mu  = (unsigned char*)(ws + OFF_MU);
    unsigned char* m1b = (unsigned char*)(ws + OFF_M1);
    short* web3 = (short*)(ws + OFF_WEB3);
    short* wpb3 = (short*)(ws + OFF_WPB3);
    short* gb   = (short*)(ws + OFF_GB);

    float* outF = (float*)d_out;
    float* pre = outF;              // [0:NOUT] pre -> xmT (halo) -> final out
    float* xm  = outF + NOUT;       // [NOUT:2NOUT] xm -> y (in-place) -> final mask
    short* xmT = (short*)d_out;     // 25.96 MB < NOUT*4

    const int N16 = XT_SHORTS/8;    // 1,622,400 16B-chunks

    k_wcvt<<<dim3(6096), dim3(256), 0, stream>>>(we, wp, gamma, web3, wpb3, gb);
    k_idwt<<<dim3(B_*C_), dim3(256), 0, stream>>>(ll, b1, b2, b3, llm, m1i, m2i, m3i, pre, mu);
    k_cast<<<dim3((NOUT + 255)/256), dim3(256), 0, stream>>>(pre, mu, wc, bcast, xm, m1b);
    k_zero16<<<dim3((N16 + 255)/256), dim3(256), 0, stream>>>((f32x4*)xmT, N16);
    k_xmt<<<dim3(3072), dim3(256), 0, stream>>>(xm, xmT);
    k_rowsum<<<dim3(B_*H_), dim3(128), 0, stream>>>(m1b, S);
    k_facm<<<dim3(NPIX/256), dim3(256), 0, stream>>>(S, fac, mh);
    k_mbconv<<<dim3(256), dim3(512), 0, stream>>>(xmT, web3, wpb3, be, bp, bcast, fac, mh, m1b, xm);
    k_gdn<<<dim3(256), dim3(512), 0, stream>>>(gb, beta, mh, outF);
}